// Round 1
// baseline (841.861 us; speedup 1.0000x reference)
//
#include <hip/hip_runtime.h>

// ---- problem constants ----
constexpr int NT   = 2048;   // tokens
constexpr int HD   = 512;    // hidden = HQ*D = HKV*D
constexpr int MBLK = 4096;   // 16^3 compression block slots
constexpr int SBLK = 512;    // 8^3 selection block slots
constexpr int NW3  = 729;    // 9^3 shifted windows
#define NEGI (-1e30f)

// =========================================================================
// token prep: coords decode, ids, bucket counts
// =========================================================================
__global__ __launch_bounds__(256) void token_prep(
    const int* __restrict__ cf, int* __restrict__ bid, int* __restrict__ sbid,
    int* __restrict__ wid, int* __restrict__ ibid, int* __restrict__ cnt,
    int* __restrict__ selcnt, int* __restrict__ wincnt) {
  int n = blockIdx.x * 256 + threadIdx.x;
  if (n >= NT) return;
  int c = cf[n];
  int x = c >> 12, y = (c >> 6) & 63, z = c & 63;
  int b  = ((x >> 2) << 8) | ((y >> 2) << 4) | (z >> 2);
  int sb = ((x >> 3) << 6) | ((y >> 3) << 3) | (z >> 3);
  int w  = ((x + 4) >> 3) * 81 + ((y + 4) >> 3) * 9 + ((z + 4) >> 3);
  int ib = ((x & 3) << 4) | ((y & 3) << 2) | (z & 3);
  bid[n] = b; sbid[n] = sb; wid[n] = w; ibid[n] = ib;
  atomicAdd(&cnt[b], 1);
  atomicAdd(&selcnt[sb], 1);
  atomicAdd(&wincnt[w], 1);
}

// =========================================================================
// single-block scans: occupied-block compaction + bucket offsets
// =========================================================================
__global__ __launch_bounds__(1024) void scan_all(
    const int* __restrict__ cnt, int* __restrict__ occ_m, int* __restrict__ inv,
    int* __restrict__ noccPtr,
    const int* __restrict__ selcnt, int* __restrict__ seloff, int* __restrict__ selpos,
    const int* __restrict__ wincnt, int* __restrict__ winoff, int* __restrict__ winpos) {
  __shared__ int buf[1024];
  int t = threadIdx.x;

  // ---- phase 1: compaction scan over MBLK=4096 (4 per thread) ----
  int base = t * 4;
  int f0 = cnt[base + 0] > 0, f1 = cnt[base + 1] > 0,
      f2 = cnt[base + 2] > 0, f3 = cnt[base + 3] > 0;
  int s = f0 + f1 + f2 + f3;
  buf[t] = s;
  __syncthreads();
  for (int off = 1; off < 1024; off <<= 1) {
    int add = (t >= off) ? buf[t - off] : 0;
    __syncthreads();
    buf[t] += add;
    __syncthreads();
  }
  int pos = buf[t] - s;
  if (f0) { occ_m[pos] = base + 0; inv[base + 0] = pos; pos++; }
  if (f1) { occ_m[pos] = base + 1; inv[base + 1] = pos; pos++; }
  if (f2) { occ_m[pos] = base + 2; inv[base + 2] = pos; pos++; }
  if (f3) { occ_m[pos] = base + 3; inv[base + 3] = pos; pos++; }
  if (t == 1023) noccPtr[0] = buf[1023];
  __syncthreads();

  // ---- phase 2: selection buckets (512) ----
  int v = (t < SBLK) ? selcnt[t] : 0;
  buf[t] = v;
  __syncthreads();
  for (int off = 1; off < 1024; off <<= 1) {
    int add = (t >= off) ? buf[t - off] : 0;
    __syncthreads();
    buf[t] += add;
    __syncthreads();
  }
  if (t < SBLK) {
    seloff[t + 1] = buf[t];
    selpos[t] = buf[t] - v;
    if (t == 0) seloff[0] = 0;
  }
  __syncthreads();

  // ---- phase 3: window buckets (729) ----
  int v2 = (t < NW3) ? wincnt[t] : 0;
  buf[t] = v2;
  __syncthreads();
  for (int off = 1; off < 1024; off <<= 1) {
    int add = (t >= off) ? buf[t - off] : 0;
    __syncthreads();
    buf[t] += add;
    __syncthreads();
  }
  if (t < NW3) {
    winoff[t + 1] = buf[t];
    winpos[t] = buf[t] - v2;
    if (t == 0) winoff[0] = 0;
  }
}

// =========================================================================
// scatter tokens into buckets
// =========================================================================
__global__ __launch_bounds__(256) void scatter(
    const int* __restrict__ sbid, const int* __restrict__ wid,
    int* __restrict__ selpos, int* __restrict__ winpos,
    int* __restrict__ sellist, int* __restrict__ winlist) {
  int n = blockIdx.x * 256 + threadIdx.x;
  if (n >= NT) return;
  int p = atomicAdd(&selpos[sbid[n]], 1);
  sellist[p] = n;
  int p2 = atomicAdd(&winpos[wid[n]], 1);
  winlist[p2] = n;
}

// =========================================================================
// generic f32 GEMM: C[rows,512] = A[rows,512] @ B[512,512]
// =========================================================================
__global__ __launch_bounds__(256) void gemm512(
    const float* __restrict__ A, const float* __restrict__ B, float* __restrict__ C,
    const int* __restrict__ nrowsPtr, int nrowsConst) {
  int nrows = nrowsPtr ? *nrowsPtr : nrowsConst;
  int rb = blockIdx.x, cb = blockIdx.y;
  int row0 = rb * 64, col0 = cb * 64;
  if (row0 >= nrows) return;
  __shared__ float As[64][17];
  __shared__ float Bs[16][68];
  int t = threadIdx.x;
  int tx = t & 15, ty = t >> 4;
  float acc[4][4] = {};
  for (int k0 = 0; k0 < 512; k0 += 16) {
    {
      int idx = t * 4; int r = idx >> 4; int kk = idx & 15;
      int gr = row0 + r;
      float4 va = (gr < nrows) ? *(const float4*)(A + (size_t)gr * 512 + k0 + kk)
                               : make_float4(0.f, 0.f, 0.f, 0.f);
      As[r][kk] = va.x; As[r][kk + 1] = va.y; As[r][kk + 2] = va.z; As[r][kk + 3] = va.w;
    }
    {
      int idx = t * 4; int kk = idx >> 6; int cc = idx & 63;
      float4 vb = *(const float4*)(B + (size_t)(k0 + kk) * 512 + col0 + cc);
      Bs[kk][cc] = vb.x; Bs[kk][cc + 1] = vb.y; Bs[kk][cc + 2] = vb.z; Bs[kk][cc + 3] = vb.w;
    }
    __syncthreads();
#pragma unroll
    for (int kk = 0; kk < 16; ++kk) {
      float a0 = As[ty * 4 + 0][kk], a1 = As[ty * 4 + 1][kk],
            a2 = As[ty * 4 + 2][kk], a3 = As[ty * 4 + 3][kk];
      float b0 = Bs[kk][tx * 4 + 0], b1 = Bs[kk][tx * 4 + 1],
            b2 = Bs[kk][tx * 4 + 2], b3 = Bs[kk][tx * 4 + 3];
      acc[0][0] += a0 * b0; acc[0][1] += a0 * b1; acc[0][2] += a0 * b2; acc[0][3] += a0 * b3;
      acc[1][0] += a1 * b0; acc[1][1] += a1 * b1; acc[1][2] += a1 * b2; acc[1][3] += a1 * b3;
      acc[2][0] += a2 * b0; acc[2][1] += a2 * b1; acc[2][2] += a2 * b2; acc[2][3] += a2 * b3;
      acc[3][0] += a3 * b0; acc[3][1] += a3 * b1; acc[3][2] += a3 * b2; acc[3][3] += a3 * b3;
    }
    __syncthreads();
  }
#pragma unroll
  for (int i = 0; i < 4; ++i) {
    int r = row0 + ty * 4 + i;
    if (r < nrows) {
#pragma unroll
      for (int j = 0; j < 4; ++j)
        C[(size_t)r * 512 + col0 + tx * 4 + j] = acc[i][j];
    }
  }
}

// =========================================================================
// gate: sigmoid(feats @ Wg)   Wg:[512,3]
// =========================================================================
__global__ __launch_bounds__(256) void gatek(
    const float* __restrict__ feats, const float* __restrict__ Wg,
    float* __restrict__ gates) {
  int idx = blockIdx.x * 256 + threadIdx.x;
  if (idx >= NT * 3) return;
  int n = idx / 3, g = idx % 3;
  const float* fp = feats + (size_t)n * 512;
  float s = 0.f;
  for (int i = 0; i < 512; ++i) s += fp[i] * Wg[i * 3 + g];
  gates[idx] = 1.f / (1.f + __expf(-s));
}

// =========================================================================
// segment accumulation into compacted block means (pre-division)
// =========================================================================
__global__ __launch_bounds__(256) void accum(
    const float* __restrict__ kf, const float* __restrict__ vf,
    const float* __restrict__ pe, const int* __restrict__ bid,
    const int* __restrict__ ibid, const int* __restrict__ inv,
    float* __restrict__ ksum, float* __restrict__ vsum) {
  int n = blockIdx.x;
  int t = threadIdx.x;
  int i = inv[bid[n]];
  const float* kp = kf + (size_t)n * 512;
  const float* vp = vf + (size_t)n * 512;
  const float* pp = pe + (size_t)ibid[n] * 512;
  float* kd = ksum + (size_t)i * 512;
  float* vd = vsum + (size_t)i * 512;
  atomicAdd(&kd[t], kp[t] + pp[t]);
  atomicAdd(&kd[t + 256], kp[t + 256] + pp[t + 256]);
  atomicAdd(&vd[t], vp[t]);
  atomicAdd(&vd[t + 256], vp[t + 256]);
}

__global__ __launch_bounds__(256) void divide_means(
    float* __restrict__ ksum, float* __restrict__ vsum,
    const int* __restrict__ occ_m, const int* __restrict__ cnt,
    const int* __restrict__ noccPtr) {
  int idx = blockIdx.x * 256 + threadIdx.x;
  int i = idx >> 9;
  if (i >= *noccPtr) return;
  float rinv = 1.f / (float)cnt[occ_m[i]];
  ksum[idx] *= rinv;
  vsum[idx] *= rinv;
}

// =========================================================================
// compressed attention over compacted blocks, 8 tokens per workgroup.
// Also accumulates per-token selection-block scores and extracts top-8.
// Writes fused = gate0 * out_c.
// =========================================================================
__global__ __launch_bounds__(256) void cattn(
    const float* __restrict__ q, const float* __restrict__ ck,
    const float* __restrict__ cv, const int* __restrict__ occ_m,
    const int* __restrict__ noccPtr, const float* __restrict__ gates,
    float* __restrict__ fused, int* __restrict__ topk_out) {
  __shared__ float qt[8 * 512];
  __shared__ float selsc[8 * 512];
  __shared__ float pmat[8][8][36];   // [h][tok][lane]
  __shared__ float mh[8][8], rlh[8][8];
  __shared__ float redV[4];
  __shared__ int   redI[4];

  const int n0 = blockIdx.x * 8;
  const int t = threadIdx.x;
  const int nocc = *noccPtr;
  const int h = t >> 5, l = t & 31;

  for (int idx = t; idx < 4096; idx += 256) {
    qt[idx] = q[(size_t)n0 * 512 + idx];
    selsc[idx] = 0.f;
  }
  __syncthreads();

  // ---- pass A: per-(head,token) running max / sumexp ----
  float mreg[8], lreg[8];
#pragma unroll
  for (int tok = 0; tok < 8; ++tok) { mreg[tok] = NEGI; lreg[tok] = 0.f; }

  for (int i0 = 0; i0 < nocc; i0 += 32) {
    int i = i0 + l;
    if (i < nocc) {
      float sacc[8];
#pragma unroll
      for (int tok = 0; tok < 8; ++tok) sacc[tok] = 0.f;
      const float4* cp = (const float4*)(ck + (size_t)i * 512 + h * 64);
#pragma unroll
      for (int d = 0; d < 16; ++d) {
        float4 a = cp[d];
#pragma unroll
        for (int tok = 0; tok < 8; ++tok) {
          float4 b = *(const float4*)(qt + tok * 512 + h * 64 + d * 4);
          sacc[tok] += a.x * b.x + a.y * b.y + a.z * b.z + a.w * b.w;
        }
      }
#pragma unroll
      for (int tok = 0; tok < 8; ++tok) {
        float sc = sacc[tok] * 0.125f;
        float nm = fmaxf(mreg[tok], sc);
        lreg[tok] = lreg[tok] * __expf(mreg[tok] - nm) + __expf(sc - nm);
        mreg[tok] = nm;
      }
    }
  }
  // reduce (m,l) across the 32 lanes of each head
#pragma unroll
  for (int tok = 0; tok < 8; ++tok) {
    float m2 = mreg[tok], l2 = lreg[tok];
#pragma unroll
    for (int s2 = 16; s2; s2 >>= 1) {
      float om = __shfl_xor(m2, s2, 64);
      float ol = __shfl_xor(l2, s2, 64);
      float nm = fmaxf(m2, om);
      l2 = l2 * __expf(m2 - nm) + ol * __expf(om - nm);
      m2 = nm;
    }
    if (l == 0) { mh[h][tok] = m2; rlh[h][tok] = 1.f / l2; }
  }
  __syncthreads();

  // ---- pass B: probs, out_c accumulation, selection scores ----
  float o0[8], o1[8];
#pragma unroll
  for (int tok = 0; tok < 8; ++tok) { o0[tok] = 0.f; o1[tok] = 0.f; }

  for (int i0 = 0; i0 < nocc; i0 += 32) {
    int i = i0 + l;
    if (i < nocc) {
      float sacc[8];
#pragma unroll
      for (int tok = 0; tok < 8; ++tok) sacc[tok] = 0.f;
      const float4* cp = (const float4*)(ck + (size_t)i * 512 + h * 64);
#pragma unroll
      for (int d = 0; d < 16; ++d) {
        float4 a = cp[d];
#pragma unroll
        for (int tok = 0; tok < 8; ++tok) {
          float4 b = *(const float4*)(qt + tok * 512 + h * 64 + d * 4);
          sacc[tok] += a.x * b.x + a.y * b.y + a.z * b.z + a.w * b.w;
        }
      }
#pragma unroll
      for (int tok = 0; tok < 8; ++tok) {
        float p = __expf(sacc[tok] * 0.125f - mh[h][tok]) * rlh[h][tok];
        pmat[h][tok][l] = p;
      }
    }
    __syncthreads();
    // selection-score accumulation (head-pooled probs into selection blocks)
    if (t < 32) {
      int i2 = i0 + t;
      if (i2 < nocc) {
        int mm2 = occ_m[i2];
        int sid = (((mm2 >> 8) >> 1) << 6) | ((((mm2 >> 4) & 15) >> 1) << 3) | ((mm2 & 15) >> 1);
#pragma unroll
        for (int tok = 0; tok < 8; ++tok) {
          float ps = 0.f;
#pragma unroll
          for (int hh = 0; hh < 8; ++hh) ps += pmat[hh][tok][t];
          atomicAdd(&selsc[tok * 512 + sid], ps);
        }
      }
    }
    // PV accumulation
    int lim = min(32, nocc - i0);
    for (int j = 0; j < lim; ++j) {
      float2 cvv = *(const float2*)(cv + (size_t)(i0 + j) * 512 + h * 64 + l * 2);
#pragma unroll
      for (int tok = 0; tok < 8; ++tok) {
        float p = pmat[h][tok][j];
        o0[tok] += p * cvv.x;
        o1[tok] += p * cvv.y;
      }
    }
    __syncthreads();
  }

  // write fused = gate0 * out_c
#pragma unroll
  for (int tok = 0; tok < 8; ++tok) {
    float g0 = gates[(n0 + tok) * 3 + 0];
    fused[(size_t)(n0 + tok) * 512 + h * 64 + l * 2]     = g0 * o0[tok];
    fused[(size_t)(n0 + tok) * 512 + h * 64 + l * 2 + 1] = g0 * o1[tok];
  }
  __syncthreads();

  // ---- top-8 selection blocks per token (value desc, index asc ties) ----
  for (int tok = 0; tok < 8; ++tok) {
    float* sp = selsc + tok * 512;
    for (int k = 0; k < 8; ++k) {
      float v0 = sp[t], v1 = sp[t + 256];
      float bv = v0; int bi = t;
      if (v1 > bv) { bv = v1; bi = t + 256; }
#pragma unroll
      for (int s2 = 32; s2; s2 >>= 1) {
        float ov = __shfl_xor(bv, s2, 64);
        int oi = __shfl_xor(bi, s2, 64);
        if (ov > bv || (ov == bv && oi < bi)) { bv = ov; bi = oi; }
      }
      if ((t & 63) == 0) { redV[t >> 6] = bv; redI[t >> 6] = bi; }
      __syncthreads();
      if (t == 0) {
        float cbv = redV[0]; int cbi = redI[0];
        for (int w2 = 1; w2 < 4; ++w2)
          if (redV[w2] > cbv || (redV[w2] == cbv && redI[w2] < cbi)) { cbv = redV[w2]; cbi = redI[w2]; }
        topk_out[(n0 + tok) * 8 + k] = cbi;
        sp[cbi] = NEGI;
      }
      __syncthreads();
    }
  }
}

// =========================================================================
// selection + window attention (sparse, bucketed), adds into fused
// =========================================================================
__global__ __launch_bounds__(64) void selwin(
    const float* __restrict__ q, const float* __restrict__ kf,
    const float* __restrict__ vf, const int* __restrict__ topk,
    const int* __restrict__ seloff, const int* __restrict__ sellist,
    const int* __restrict__ winoff, const int* __restrict__ winlist,
    const int* __restrict__ wid_tok, const float* __restrict__ gates,
    float* __restrict__ fused) {
  int n = blockIdx.x, t = threadIdx.x;
  int h = t >> 3, j = t & 7;
  float q8[8];
  const float* qp = q + (size_t)n * 512 + h * 64 + j * 8;
#pragma unroll
  for (int d = 0; d < 8; ++d) q8[d] = qp[d];

  // ---- selection branch ----
  float os[8];
#pragma unroll
  for (int d = 0; d < 8; ++d) os[d] = 0.f;
  float m = NEGI, lsum = 0.f;
  for (int k = 0; k < 8; ++k) {
    int s = topk[n * 8 + k];
    int e0 = seloff[s], e1 = seloff[s + 1];
    for (int idx = e0; idx < e1; ++idx) {
      int tj = sellist[idx];
      const float* kp = kf + (size_t)tj * 512 + h * 64 + j * 8;
      float part = 0.f;
#pragma unroll
      for (int d = 0; d < 8; ++d) part += q8[d] * kp[d];
      part += __shfl_xor(part, 1, 64);
      part += __shfl_xor(part, 2, 64);
      part += __shfl_xor(part, 4, 64);
      float sc = part * 0.125f;
      float nm = fmaxf(m, sc);
      float scale = __expf(m - nm);
      float pv = __expf(sc - nm);
      const float* vp = vf + (size_t)tj * 512 + h * 64 + j * 8;
      lsum = lsum * scale + pv;
#pragma unroll
      for (int d = 0; d < 8; ++d) os[d] = os[d] * scale + pv * vp[d];
      m = nm;
    }
  }
  {
    float rl = (lsum > 0.f) ? 1.f / lsum : 0.f;
#pragma unroll
    for (int d = 0; d < 8; ++d) os[d] *= rl;
  }

  // ---- window branch ----
  float ow[8];
#pragma unroll
  for (int d = 0; d < 8; ++d) ow[d] = 0.f;
  m = NEGI; lsum = 0.f;
  int w = wid_tok[n];
  int e0 = winoff[w], e1 = winoff[w + 1];
  for (int idx = e0; idx < e1; ++idx) {
    int tj = winlist[idx];
    const float* kp = kf + (size_t)tj * 512 + h * 64 + j * 8;
    float part = 0.f;
#pragma unroll
    for (int d = 0; d < 8; ++d) part += q8[d] * kp[d];
    part += __shfl_xor(part, 1, 64);
    part += __shfl_xor(part, 2, 64);
    part += __shfl_xor(part, 4, 64);
    float sc = part * 0.125f;
    float nm = fmaxf(m, sc);
    float scale = __expf(m - nm);
    float pv = __expf(sc - nm);
    const float* vp = vf + (size_t)tj * 512 + h * 64 + j * 8;
    lsum = lsum * scale + pv;
#pragma unroll
    for (int d = 0; d < 8; ++d) ow[d] = ow[d] * scale + pv * vp[d];
    m = nm;
  }
  {
    float rl = (lsum > 0.f) ? 1.f / lsum : 0.f;
#pragma unroll
    for (int d = 0; d < 8; ++d) ow[d] *= rl;
  }

  float g1 = gates[n * 3 + 1], g2 = gates[n * 3 + 2];
  float* fp = fused + (size_t)n * 512 + h * 64 + j * 8;
#pragma unroll
  for (int d = 0; d < 8; ++d) fp[d] += g1 * os[d] + g2 * ow[d];
}

// =========================================================================
// launcher
// =========================================================================
extern "C" void kernel_launch(void* const* d_in, const int* in_sizes, int n_in,
                              void* d_out, int out_size, void* d_ws, size_t ws_size,
                              hipStream_t stream) {
  const float* feats = (const float*)d_in[0];
  const int* coords  = (const int*)d_in[1];
  const float* Wq  = (const float*)d_in[2];
  const float* Wk  = (const float*)d_in[3];
  const float* Wv  = (const float*)d_in[4];
  const float* Wo  = (const float*)d_in[5];
  const float* Wck = (const float*)d_in[6];
  const float* Wcv = (const float*)d_in[7];
  const float* pe  = (const float*)d_in[8];
  const float* Wg  = (const float*)d_in[9];
  float* out = (float*)d_out;

  char* p = (char*)d_ws;
  auto alloc = [&](size_t bytes) -> char* {
    char* r = p;
    p += (bytes + 255) & ~(size_t)255;
    return r;
  };
  float* q     = (float*)alloc((size_t)NT * 512 * 4);
  float* kf    = (float*)alloc((size_t)NT * 512 * 4);
  float* vf    = (float*)alloc((size_t)NT * 512 * 4);
  float* fused = (float*)alloc((size_t)NT * 512 * 4);
  float* zf    = (float*)alloc((size_t)2 * NT * 512 * 4);  // ckbar|cvbar (zeroed)
  float* ckbar = zf;
  float* cvbar = zf + (size_t)NT * 512;
  float* ckc   = (float*)alloc((size_t)NT * 512 * 4);
  float* cvc   = (float*)alloc((size_t)NT * 512 * 4);
  float* gates = (float*)alloc((size_t)NT * 3 * 4);
  int* zi      = (int*)alloc((size_t)(MBLK + SBLK + NW3) * 4);  // cnt|selcnt|wincnt (zeroed)
  int* cnt = zi;
  int* selcnt = zi + MBLK;
  int* wincnt = zi + MBLK + SBLK;
  int* inv     = (int*)alloc((size_t)MBLK * 4);
  int* occ     = (int*)alloc((size_t)NT * 4);
  int* nocc    = (int*)alloc(4);
  int* bid     = (int*)alloc((size_t)NT * 4);
  int* sbid    = (int*)alloc((size_t)NT * 4);
  int* wid     = (int*)alloc((size_t)NT * 4);
  int* ibid    = (int*)alloc((size_t)NT * 4);
  int* seloff  = (int*)alloc((size_t)(SBLK + 1) * 4);
  int* selpos  = (int*)alloc((size_t)SBLK * 4);
  int* sellist = (int*)alloc((size_t)NT * 4);
  int* winoff  = (int*)alloc((size_t)(NW3 + 1) * 4);
  int* winpos  = (int*)alloc((size_t)NW3 * 4);
  int* winlist = (int*)alloc((size_t)NT * 4);
  int* topk    = (int*)alloc((size_t)NT * 8 * 4);

  hipMemsetAsync(zf, 0, (size_t)2 * NT * 512 * 4, stream);
  hipMemsetAsync(zi, 0, (size_t)(MBLK + SBLK + NW3) * 4, stream);

  token_prep<<<8, 256, 0, stream>>>(coords, bid, sbid, wid, ibid, cnt, selcnt, wincnt);
  scan_all<<<1, 1024, 0, stream>>>(cnt, occ, inv, nocc, selcnt, seloff, selpos,
                                   wincnt, winoff, winpos);
  scatter<<<8, 256, 0, stream>>>(sbid, wid, selpos, winpos, sellist, winlist);

  dim3 gg(32, 8);
  gemm512<<<gg, 256, 0, stream>>>(feats, Wq, q, nullptr, NT);
  gemm512<<<gg, 256, 0, stream>>>(feats, Wk, kf, nullptr, NT);
  gemm512<<<gg, 256, 0, stream>>>(feats, Wv, vf, nullptr, NT);
  gatek<<<24, 256, 0, stream>>>(feats, Wg, gates);

  accum<<<NT, 256, 0, stream>>>(kf, vf, pe, bid, ibid, inv, ckbar, cvbar);
  divide_means<<<4096, 256, 0, stream>>>(ckbar, cvbar, occ, cnt, nocc);
  gemm512<<<gg, 256, 0, stream>>>(ckbar, Wck, ckc, nocc, 0);
  gemm512<<<gg, 256, 0, stream>>>(cvbar, Wcv, cvc, nocc, 0);

  cattn<<<256, 256, 0, stream>>>(q, ckc, cvc, occ, nocc, gates, fused, topk);
  selwin<<<NT, 64, 0, stream>>>(q, kf, vf, topk, seloff, sellist, winoff, winlist,
                                wid, gates, fused);
  gemm512<<<gg, 256, 0, stream>>>(fused, Wo, out, nullptr, NT);
}

// Round 2
// 789.725 us; speedup vs baseline: 1.0660x; 1.0660x over previous
//
#include <hip/hip_runtime.h>

// ---- problem constants ----
constexpr int NT   = 2048;   // tokens
constexpr int HD   = 512;    // hidden = HQ*D = HKV*D
constexpr int MBLK = 4096;   // 16^3 compression block slots
constexpr int SBLK = 512;    // 8^3 selection block slots
constexpr int NW3  = 729;    // 9^3 shifted windows
#define NEGI (-1e30f)

// =========================================================================
// token prep: coords decode, ids, bucket counts
// =========================================================================
__global__ __launch_bounds__(256) void token_prep(
    const int* __restrict__ cf, int* __restrict__ bid, int* __restrict__ sbid,
    int* __restrict__ wid, int* __restrict__ ibid, int* __restrict__ cnt,
    int* __restrict__ selcnt, int* __restrict__ wincnt) {
  int n = blockIdx.x * 256 + threadIdx.x;
  if (n >= NT) return;
  int c = cf[n];
  int x = c >> 12, y = (c >> 6) & 63, z = c & 63;
  int b  = ((x >> 2) << 8) | ((y >> 2) << 4) | (z >> 2);
  int sb = ((x >> 3) << 6) | ((y >> 3) << 3) | (z >> 3);
  int w  = ((x + 4) >> 3) * 81 + ((y + 4) >> 3) * 9 + ((z + 4) >> 3);
  int ib = ((x & 3) << 4) | ((y & 3) << 2) | (z & 3);
  bid[n] = b; sbid[n] = sb; wid[n] = w; ibid[n] = ib;
  atomicAdd(&cnt[b], 1);
  atomicAdd(&selcnt[sb], 1);
  atomicAdd(&wincnt[w], 1);
}

// =========================================================================
// single-block scans: occupied-block compaction + bucket offsets
// =========================================================================
__global__ __launch_bounds__(1024) void scan_all(
    const int* __restrict__ cnt, int* __restrict__ occ_m, int* __restrict__ inv,
    int* __restrict__ noccPtr,
    const int* __restrict__ selcnt, int* __restrict__ seloff, int* __restrict__ selpos,
    const int* __restrict__ wincnt, int* __restrict__ winoff, int* __restrict__ winpos) {
  __shared__ int buf[1024];
  int t = threadIdx.x;

  // ---- phase 1: compaction scan over MBLK=4096 (4 per thread) ----
  int base = t * 4;
  int f0 = cnt[base + 0] > 0, f1 = cnt[base + 1] > 0,
      f2 = cnt[base + 2] > 0, f3 = cnt[base + 3] > 0;
  int s = f0 + f1 + f2 + f3;
  buf[t] = s;
  __syncthreads();
  for (int off = 1; off < 1024; off <<= 1) {
    int add = (t >= off) ? buf[t - off] : 0;
    __syncthreads();
    buf[t] += add;
    __syncthreads();
  }
  int pos = buf[t] - s;
  if (f0) { occ_m[pos] = base + 0; inv[base + 0] = pos; pos++; }
  if (f1) { occ_m[pos] = base + 1; inv[base + 1] = pos; pos++; }
  if (f2) { occ_m[pos] = base + 2; inv[base + 2] = pos; pos++; }
  if (f3) { occ_m[pos] = base + 3; inv[base + 3] = pos; pos++; }
  if (t == 1023) noccPtr[0] = buf[1023];
  __syncthreads();

  // ---- phase 2: selection buckets (512) ----
  int v = (t < SBLK) ? selcnt[t] : 0;
  buf[t] = v;
  __syncthreads();
  for (int off = 1; off < 1024; off <<= 1) {
    int add = (t >= off) ? buf[t - off] : 0;
    __syncthreads();
    buf[t] += add;
    __syncthreads();
  }
  if (t < SBLK) {
    seloff[t + 1] = buf[t];
    selpos[t] = buf[t] - v;
    if (t == 0) seloff[0] = 0;
  }
  __syncthreads();

  // ---- phase 3: window buckets (729) ----
  int v2 = (t < NW3) ? wincnt[t] : 0;
  buf[t] = v2;
  __syncthreads();
  for (int off = 1; off < 1024; off <<= 1) {
    int add = (t >= off) ? buf[t - off] : 0;
    __syncthreads();
    buf[t] += add;
    __syncthreads();
  }
  if (t < NW3) {
    winoff[t + 1] = buf[t];
    winpos[t] = buf[t] - v2;
    if (t == 0) winoff[0] = 0;
  }
}

// =========================================================================
// scatter tokens into buckets
// =========================================================================
__global__ __launch_bounds__(256) void scatter(
    const int* __restrict__ sbid, const int* __restrict__ wid,
    int* __restrict__ selpos, int* __restrict__ winpos,
    int* __restrict__ sellist, int* __restrict__ winlist) {
  int n = blockIdx.x * 256 + threadIdx.x;
  if (n >= NT) return;
  int p = atomicAdd(&selpos[sbid[n]], 1);
  sellist[p] = n;
  int p2 = atomicAdd(&winpos[wid[n]], 1);
  winlist[p2] = n;
}

// =========================================================================
// generic f32 GEMM: C[rows,512] = A[rows,512] @ B[512,512]
// =========================================================================
__global__ __launch_bounds__(256) void gemm512(
    const float* __restrict__ A, const float* __restrict__ B, float* __restrict__ C,
    const int* __restrict__ nrowsPtr, int nrowsConst) {
  int nrows = nrowsPtr ? *nrowsPtr : nrowsConst;
  int rb = blockIdx.x, cb = blockIdx.y;
  int row0 = rb * 64, col0 = cb * 64;
  if (row0 >= nrows) return;
  __shared__ float As[64][17];
  __shared__ float Bs[16][68];
  int t = threadIdx.x;
  int tx = t & 15, ty = t >> 4;
  float acc[4][4] = {};
  for (int k0 = 0; k0 < 512; k0 += 16) {
    {
      int idx = t * 4; int r = idx >> 4; int kk = idx & 15;
      int gr = row0 + r;
      float4 va = (gr < nrows) ? *(const float4*)(A + (size_t)gr * 512 + k0 + kk)
                               : make_float4(0.f, 0.f, 0.f, 0.f);
      As[r][kk] = va.x; As[r][kk + 1] = va.y; As[r][kk + 2] = va.z; As[r][kk + 3] = va.w;
    }
    {
      int idx = t * 4; int kk = idx >> 6; int cc = idx & 63;
      float4 vb = *(const float4*)(B + (size_t)(k0 + kk) * 512 + col0 + cc);
      Bs[kk][cc] = vb.x; Bs[kk][cc + 1] = vb.y; Bs[kk][cc + 2] = vb.z; Bs[kk][cc + 3] = vb.w;
    }
    __syncthreads();
#pragma unroll
    for (int kk = 0; kk < 16; ++kk) {
      float a0 = As[ty * 4 + 0][kk], a1 = As[ty * 4 + 1][kk],
            a2 = As[ty * 4 + 2][kk], a3 = As[ty * 4 + 3][kk];
      float b0 = Bs[kk][tx * 4 + 0], b1 = Bs[kk][tx * 4 + 1],
            b2 = Bs[kk][tx * 4 + 2], b3 = Bs[kk][tx * 4 + 3];
      acc[0][0] += a0 * b0; acc[0][1] += a0 * b1; acc[0][2] += a0 * b2; acc[0][3] += a0 * b3;
      acc[1][0] += a1 * b0; acc[1][1] += a1 * b1; acc[1][2] += a1 * b2; acc[1][3] += a1 * b3;
      acc[2][0] += a2 * b0; acc[2][1] += a2 * b1; acc[2][2] += a2 * b2; acc[2][3] += a2 * b3;
      acc[3][0] += a3 * b0; acc[3][1] += a3 * b1; acc[3][2] += a3 * b2; acc[3][3] += a3 * b3;
    }
    __syncthreads();
  }
#pragma unroll
  for (int i = 0; i < 4; ++i) {
    int r = row0 + ty * 4 + i;
    if (r < nrows) {
#pragma unroll
      for (int j = 0; j < 4; ++j)
        C[(size_t)r * 512 + col0 + tx * 4 + j] = acc[i][j];
    }
  }
}

// =========================================================================
// gate: sigmoid(feats @ Wg)   Wg:[512,3]
// =========================================================================
__global__ __launch_bounds__(256) void gatek(
    const float* __restrict__ feats, const float* __restrict__ Wg,
    float* __restrict__ gates) {
  int idx = blockIdx.x * 256 + threadIdx.x;
  if (idx >= NT * 3) return;
  int n = idx / 3, g = idx % 3;
  const float* fp = feats + (size_t)n * 512;
  float s = 0.f;
  for (int i = 0; i < 512; ++i) s += fp[i] * Wg[i * 3 + g];
  gates[idx] = 1.f / (1.f + __expf(-s));
}

// =========================================================================
// segment accumulation into compacted block means (pre-division)
// =========================================================================
__global__ __launch_bounds__(256) void accum(
    const float* __restrict__ kf, const float* __restrict__ vf,
    const float* __restrict__ pe, const int* __restrict__ bid,
    const int* __restrict__ ibid, const int* __restrict__ inv,
    float* __restrict__ ksum, float* __restrict__ vsum) {
  int n = blockIdx.x;
  int t = threadIdx.x;
  int i = inv[bid[n]];
  const float* kp = kf + (size_t)n * 512;
  const float* vp = vf + (size_t)n * 512;
  const float* pp = pe + (size_t)ibid[n] * 512;
  float* kd = ksum + (size_t)i * 512;
  float* vd = vsum + (size_t)i * 512;
  atomicAdd(&kd[t], kp[t] + pp[t]);
  atomicAdd(&kd[t + 256], kp[t + 256] + pp[t + 256]);
  atomicAdd(&vd[t], vp[t]);
  atomicAdd(&vd[t + 256], vp[t + 256]);
}

__global__ __launch_bounds__(256) void divide_means(
    float* __restrict__ ksum, float* __restrict__ vsum,
    const int* __restrict__ occ_m, const int* __restrict__ cnt,
    const int* __restrict__ noccPtr) {
  int idx = blockIdx.x * 256 + threadIdx.x;
  int i = idx >> 9;
  if (i >= *noccPtr) return;
  float rinv = 1.f / (float)cnt[occ_m[i]];
  ksum[idx] *= rinv;
  vsum[idx] *= rinv;
}

// =========================================================================
// compressed attention v2: 512 threads (one wave per head), 64-key tiles,
// shift-free softmax (C=0: scores are bounded so exp() cannot overflow).
// Two passes: A computes per-(head,tok) sumexp l; B computes p, PV, and
// head-pooled selection scores, then top-8 extraction. fused = gate0*out_c.
// =========================================================================
__global__ __launch_bounds__(512) void cattn(
    const float* __restrict__ q, const float* __restrict__ ck,
    const float* __restrict__ cv, const int* __restrict__ occ_m,
    const int* __restrict__ noccPtr, const float* __restrict__ gates,
    float* __restrict__ fused, int* __restrict__ topk_out) {
  __shared__ float qt[8 * 512];      // 16 KB: q rows for 8 tokens
  __shared__ float selsc[8 * 512];   // 16 KB: selection scores per token
  __shared__ float pmat[8][8][68];   // 17.4 KB: [head][tok][key j] (row 16B-aligned)
  __shared__ float rlh[8][8];        // 1/l per (head, tok)
  __shared__ int   sid_l[64];        // selection-block id of tile keys
  __shared__ float redV[8];
  __shared__ int   redI[8];

  const int n0 = blockIdx.x * 8;
  const int t = threadIdx.x;
  const int nocc = *noccPtr;
  const int h = t >> 6, l = t & 63;   // wave == head

  for (int idx = t; idx < 4096; idx += 512) {
    qt[idx] = q[(size_t)n0 * 512 + idx];
    selsc[idx] = 0.f;
  }
  __syncthreads();

  // ---- pass A: l = sum(exp(sc)) per (head, tok) ----
  float lacc[8];
#pragma unroll
  for (int tok = 0; tok < 8; ++tok) lacc[tok] = 0.f;

  for (int i0 = 0; i0 < nocc; i0 += 64) {
    int i = i0 + l;
    if (i < nocc) {
      float sacc[8];
#pragma unroll
      for (int tok = 0; tok < 8; ++tok) sacc[tok] = 0.f;
      const float4* cp = (const float4*)(ck + (size_t)i * 512 + h * 64);
#pragma unroll
      for (int d = 0; d < 16; ++d) {
        float4 a = cp[d];
#pragma unroll
        for (int tok = 0; tok < 8; ++tok) {
          float4 b = *(const float4*)(qt + tok * 512 + h * 64 + d * 4);
          sacc[tok] += a.x * b.x + a.y * b.y + a.z * b.z + a.w * b.w;
        }
      }
#pragma unroll
      for (int tok = 0; tok < 8; ++tok)
        lacc[tok] += __expf(sacc[tok] * 0.125f);
    }
  }
#pragma unroll
  for (int tok = 0; tok < 8; ++tok) {
    float l2 = lacc[tok];
#pragma unroll
    for (int s2 = 32; s2; s2 >>= 1) l2 += __shfl_xor(l2, s2, 64);
    if (l == 0) rlh[h][tok] = 1.f / l2;
  }
  __syncthreads();

  // ---- pass B: p, PV, selection scores ----
  float rl[8];
#pragma unroll
  for (int tok = 0; tok < 8; ++tok) rl[tok] = rlh[h][tok];
  float o[8];
#pragma unroll
  for (int tok = 0; tok < 8; ++tok) o[tok] = 0.f;

  for (int i0 = 0; i0 < nocc; i0 += 64) {
    int lim = min(64, nocc - i0);
    int i = i0 + l;
    float p[8];
    if (i < nocc) {
      float sacc[8];
#pragma unroll
      for (int tok = 0; tok < 8; ++tok) sacc[tok] = 0.f;
      const float4* cp = (const float4*)(ck + (size_t)i * 512 + h * 64);
#pragma unroll
      for (int d = 0; d < 16; ++d) {
        float4 a = cp[d];
#pragma unroll
        for (int tok = 0; tok < 8; ++tok) {
          float4 b = *(const float4*)(qt + tok * 512 + h * 64 + d * 4);
          sacc[tok] += a.x * b.x + a.y * b.y + a.z * b.z + a.w * b.w;
        }
      }
#pragma unroll
      for (int tok = 0; tok < 8; ++tok)
        p[tok] = __expf(sacc[tok] * 0.125f) * rl[tok];
    }
    __syncthreads();   // previous tile's pmat consumers are done
    if (i < nocc) {
#pragma unroll
      for (int tok = 0; tok < 8; ++tok) pmat[h][tok][l] = p[tok];
    }
    if (t < 64 && t < lim) {
      int mm2 = occ_m[i0 + t];
      sid_l[t] = (((mm2 >> 8) >> 1) << 6) | ((((mm2 >> 4) & 15) >> 1) << 3) | ((mm2 & 15) >> 1);
    }
    __syncthreads();
    // selection-score accumulation: thread = (j = t&63, tok = t>>6)
    {
      int j = t & 63, tk = t >> 6;
      if (j < lim) {
        float ps = 0.f;
#pragma unroll
        for (int hh = 0; hh < 8; ++hh) ps += pmat[hh][tk][j];
        atomicAdd(&selsc[tk * 512 + sid_l[j]], ps);
      }
    }
    // PV: lane = output dim
    {
      const float* cvp = cv + (size_t)i0 * 512 + h * 64 + l;
      int g4 = lim >> 2;
      for (int g = 0; g < g4; ++g) {
        float v0 = cvp[(size_t)(g * 4 + 0) * 512];
        float v1 = cvp[(size_t)(g * 4 + 1) * 512];
        float v2 = cvp[(size_t)(g * 4 + 2) * 512];
        float v3 = cvp[(size_t)(g * 4 + 3) * 512];
#pragma unroll
        for (int tok = 0; tok < 8; ++tok) {
          float4 pm = *(const float4*)(&pmat[h][tok][g * 4]);
          o[tok] += pm.x * v0 + pm.y * v1 + pm.z * v2 + pm.w * v3;
        }
      }
      for (int j = g4 * 4; j < lim; ++j) {
        float v = cvp[(size_t)j * 512];
#pragma unroll
        for (int tok = 0; tok < 8; ++tok) o[tok] += pmat[h][tok][j] * v;
      }
    }
  }

  // write fused = gate0 * out_c
#pragma unroll
  for (int tok = 0; tok < 8; ++tok) {
    float g0 = gates[(n0 + tok) * 3 + 0];
    fused[(size_t)(n0 + tok) * 512 + h * 64 + l] = g0 * o[tok];
  }
  __syncthreads();

  // ---- top-8 selection blocks per token (value desc, index asc ties) ----
  for (int tok = 0; tok < 8; ++tok) {
    float* sp = selsc + tok * 512;
    for (int k = 0; k < 8; ++k) {
      float bv = sp[t]; int bi = t;
#pragma unroll
      for (int s2 = 32; s2; s2 >>= 1) {
        float ov = __shfl_xor(bv, s2, 64);
        int oi = __shfl_xor(bi, s2, 64);
        if (ov > bv || (ov == bv && oi < bi)) { bv = ov; bi = oi; }
      }
      if (l == 0) { redV[h] = bv; redI[h] = bi; }
      __syncthreads();
      if (t == 0) {
        float cbv = redV[0]; int cbi = redI[0];
        for (int w2 = 1; w2 < 8; ++w2)
          if (redV[w2] > cbv || (redV[w2] == cbv && redI[w2] < cbi)) { cbv = redV[w2]; cbi = redI[w2]; }
        topk_out[(n0 + tok) * 8 + k] = cbi;
        sp[cbi] = NEGI;
      }
      __syncthreads();
    }
  }
}

// =========================================================================
// selection + window attention (sparse, bucketed), adds into fused
// =========================================================================
__global__ __launch_bounds__(64) void selwin(
    const float* __restrict__ q, const float* __restrict__ kf,
    const float* __restrict__ vf, const int* __restrict__ topk,
    const int* __restrict__ seloff, const int* __restrict__ sellist,
    const int* __restrict__ winoff, const int* __restrict__ winlist,
    const int* __restrict__ wid_tok, const float* __restrict__ gates,
    float* __restrict__ fused) {
  int n = blockIdx.x, t = threadIdx.x;
  int h = t >> 3, j = t & 7;
  float q8[8];
  const float* qp = q + (size_t)n * 512 + h * 64 + j * 8;
#pragma unroll
  for (int d = 0; d < 8; ++d) q8[d] = qp[d];

  // ---- selection branch ----
  float os[8];
#pragma unroll
  for (int d = 0; d < 8; ++d) os[d] = 0.f;
  float m = NEGI, lsum = 0.f;
  for (int k = 0; k < 8; ++k) {
    int s = topk[n * 8 + k];
    int e0 = seloff[s], e1 = seloff[s + 1];
    for (int idx = e0; idx < e1; ++idx) {
      int tj = sellist[idx];
      const float* kp = kf + (size_t)tj * 512 + h * 64 + j * 8;
      float part = 0.f;
#pragma unroll
      for (int d = 0; d < 8; ++d) part += q8[d] * kp[d];
      part += __shfl_xor(part, 1, 64);
      part += __shfl_xor(part, 2, 64);
      part += __shfl_xor(part, 4, 64);
      float sc = part * 0.125f;
      float nm = fmaxf(m, sc);
      float scale = __expf(m - nm);
      float pv = __expf(sc - nm);
      const float* vp = vf + (size_t)tj * 512 + h * 64 + j * 8;
      lsum = lsum * scale + pv;
#pragma unroll
      for (int d = 0; d < 8; ++d) os[d] = os[d] * scale + pv * vp[d];
      m = nm;
    }
  }
  {
    float rl = (lsum > 0.f) ? 1.f / lsum : 0.f;
#pragma unroll
    for (int d = 0; d < 8; ++d) os[d] *= rl;
  }

  // ---- window branch ----
  float ow[8];
#pragma unroll
  for (int d = 0; d < 8; ++d) ow[d] = 0.f;
  m = NEGI; lsum = 0.f;
  int w = wid_tok[n];
  int e0 = winoff[w], e1 = winoff[w + 1];
  for (int idx = e0; idx < e1; ++idx) {
    int tj = winlist[idx];
    const float* kp = kf + (size_t)tj * 512 + h * 64 + j * 8;
    float part = 0.f;
#pragma unroll
    for (int d = 0; d < 8; ++d) part += q8[d] * kp[d];
    part += __shfl_xor(part, 1, 64);
    part += __shfl_xor(part, 2, 64);
    part += __shfl_xor(part, 4, 64);
    float sc = part * 0.125f;
    float nm = fmaxf(m, sc);
    float scale = __expf(m - nm);
    float pv = __expf(sc - nm);
    const float* vp = vf + (size_t)tj * 512 + h * 64 + j * 8;
    lsum = lsum * scale + pv;
#pragma unroll
    for (int d = 0; d < 8; ++d) ow[d] = ow[d] * scale + pv * vp[d];
    m = nm;
  }
  {
    float rl = (lsum > 0.f) ? 1.f / lsum : 0.f;
#pragma unroll
    for (int d = 0; d < 8; ++d) ow[d] *= rl;
  }

  float g1 = gates[n * 3 + 1], g2 = gates[n * 3 + 2];
  float* fp = fused + (size_t)n * 512 + h * 64 + j * 8;
#pragma unroll
  for (int d = 0; d < 8; ++d) fp[d] += g1 * os[d] + g2 * ow[d];
}

// =========================================================================
// launcher
// =========================================================================
extern "C" void kernel_launch(void* const* d_in, const int* in_sizes, int n_in,
                              void* d_out, int out_size, void* d_ws, size_t ws_size,
                              hipStream_t stream) {
  const float* feats = (const float*)d_in[0];
  const int* coords  = (const int*)d_in[1];
  const float* Wq  = (const float*)d_in[2];
  const float* Wk  = (const float*)d_in[3];
  const float* Wv  = (const float*)d_in[4];
  const float* Wo  = (const float*)d_in[5];
  const float* Wck = (const float*)d_in[6];
  const float* Wcv = (const float*)d_in[7];
  const float* pe  = (const float*)d_in[8];
  const float* Wg  = (const float*)d_in[9];
  float* out = (float*)d_out;

  char* p = (char*)d_ws;
  auto alloc = [&](size_t bytes) -> char* {
    char* r = p;
    p += (bytes + 255) & ~(size_t)255;
    return r;
  };
  float* q     = (float*)alloc((size_t)NT * 512 * 4);
  float* kf    = (float*)alloc((size_t)NT * 512 * 4);
  float* vf    = (float*)alloc((size_t)NT * 512 * 4);
  float* fused = (float*)alloc((size_t)NT * 512 * 4);
  float* zf    = (float*)alloc((size_t)2 * NT * 512 * 4);  // ckbar|cvbar (zeroed)
  float* ckbar = zf;
  float* cvbar = zf + (size_t)NT * 512;
  float* ckc   = (float*)alloc((size_t)NT * 512 * 4);
  float* cvc   = (float*)alloc((size_t)NT * 512 * 4);
  float* gates = (float*)alloc((size_t)NT * 3 * 4);
  int* zi      = (int*)alloc((size_t)(MBLK + SBLK + NW3) * 4);  // cnt|selcnt|wincnt (zeroed)
  int* cnt = zi;
  int* selcnt = zi + MBLK;
  int* wincnt = zi + MBLK + SBLK;
  int* inv     = (int*)alloc((size_t)MBLK * 4);
  int* occ     = (int*)alloc((size_t)NT * 4);
  int* nocc    = (int*)alloc(4);
  int* bid     = (int*)alloc((size_t)NT * 4);
  int* sbid    = (int*)alloc((size_t)NT * 4);
  int* wid     = (int*)alloc((size_t)NT * 4);
  int* ibid    = (int*)alloc((size_t)NT * 4);
  int* seloff  = (int*)alloc((size_t)(SBLK + 1) * 4);
  int* selpos  = (int*)alloc((size_t)SBLK * 4);
  int* sellist = (int*)alloc((size_t)NT * 4);
  int* winoff  = (int*)alloc((size_t)(NW3 + 1) * 4);
  int* winpos  = (int*)alloc((size_t)NW3 * 4);
  int* winlist = (int*)alloc((size_t)NT * 4);
  int* topk    = (int*)alloc((size_t)NT * 8 * 4);

  hipMemsetAsync(zf, 0, (size_t)2 * NT * 512 * 4, stream);
  hipMemsetAsync(zi, 0, (size_t)(MBLK + SBLK + NW3) * 4, stream);

  token_prep<<<8, 256, 0, stream>>>(coords, bid, sbid, wid, ibid, cnt, selcnt, wincnt);
  scan_all<<<1, 1024, 0, stream>>>(cnt, occ, inv, nocc, selcnt, seloff, selpos,
                                   wincnt, winoff, winpos);
  scatter<<<8, 256, 0, stream>>>(sbid, wid, selpos, winpos, sellist, winlist);

  dim3 gg(32, 8);
  gemm512<<<gg, 256, 0, stream>>>(feats, Wq, q, nullptr, NT);
  gemm512<<<gg, 256, 0, stream>>>(feats, Wk, kf, nullptr, NT);
  gemm512<<<gg, 256, 0, stream>>>(feats, Wv, vf, nullptr, NT);
  gatek<<<24, 256, 0, stream>>>(feats, Wg, gates);

  accum<<<NT, 256, 0, stream>>>(kf, vf, pe, bid, ibid, inv, ckbar, cvbar);
  divide_means<<<4096, 256, 0, stream>>>(ckbar, cvbar, occ, cnt, nocc);
  gemm512<<<gg, 256, 0, stream>>>(ckbar, Wck, ckc, nocc, 0);
  gemm512<<<gg, 256, 0, stream>>>(cvbar, Wcv, cvc, nocc, 0);

  cattn<<<256, 512, 0, stream>>>(q, ckc, cvc, occ, nocc, gates, fused, topk);
  selwin<<<NT, 64, 0, stream>>>(q, kf, vf, topk, seloff, sellist, winoff, winlist,
                                wid, gates, fused);
  gemm512<<<gg, 256, 0, stream>>>(fused, Wo, out, nullptr, NT);
}

// Round 3
// 650.946 us; speedup vs baseline: 1.2933x; 1.2132x over previous
//
#include <hip/hip_runtime.h>

// ---- problem constants ----
constexpr int NT   = 2048;   // tokens
constexpr int HD   = 512;    // hidden = HQ*D = HKV*D
constexpr int MBLK = 4096;   // 16^3 compression block slots
constexpr int SBLK = 512;    // 8^3 selection block slots
constexpr int NW3  = 729;    // 9^3 shifted windows
constexpr int KPAD = 2048;   // padded key stride for ckT
#define NEGI (-1e30f)

// =========================================================================
// token prep: coords decode, ids, bucket counts
// =========================================================================
__global__ __launch_bounds__(256) void token_prep(
    const int* __restrict__ cf, int* __restrict__ bid, int* __restrict__ sbid,
    int* __restrict__ wid, int* __restrict__ ibid, int* __restrict__ cnt,
    int* __restrict__ selcnt, int* __restrict__ wincnt) {
  int n = blockIdx.x * 256 + threadIdx.x;
  if (n >= NT) return;
  int c = cf[n];
  int x = c >> 12, y = (c >> 6) & 63, z = c & 63;
  int b  = ((x >> 2) << 8) | ((y >> 2) << 4) | (z >> 2);
  int sb = ((x >> 3) << 6) | ((y >> 3) << 3) | (z >> 3);
  int w  = ((x + 4) >> 3) * 81 + ((y + 4) >> 3) * 9 + ((z + 4) >> 3);
  int ib = ((x & 3) << 4) | ((y & 3) << 2) | (z & 3);
  bid[n] = b; sbid[n] = sb; wid[n] = w; ibid[n] = ib;
  atomicAdd(&cnt[b], 1);
  atomicAdd(&selcnt[sb], 1);
  atomicAdd(&wincnt[w], 1);
}

// =========================================================================
// single-block scans: occupied-block compaction + bucket offsets
// =========================================================================
__global__ __launch_bounds__(1024) void scan_all(
    const int* __restrict__ cnt, int* __restrict__ occ_m, int* __restrict__ inv,
    int* __restrict__ noccPtr,
    const int* __restrict__ selcnt, int* __restrict__ seloff, int* __restrict__ selpos,
    const int* __restrict__ wincnt, int* __restrict__ winoff, int* __restrict__ winpos) {
  __shared__ int buf[1024];
  int t = threadIdx.x;

  // ---- phase 1: compaction scan over MBLK=4096 (4 per thread) ----
  int base = t * 4;
  int f0 = cnt[base + 0] > 0, f1 = cnt[base + 1] > 0,
      f2 = cnt[base + 2] > 0, f3 = cnt[base + 3] > 0;
  int s = f0 + f1 + f2 + f3;
  buf[t] = s;
  __syncthreads();
  for (int off = 1; off < 1024; off <<= 1) {
    int add = (t >= off) ? buf[t - off] : 0;
    __syncthreads();
    buf[t] += add;
    __syncthreads();
  }
  int pos = buf[t] - s;
  if (f0) { occ_m[pos] = base + 0; inv[base + 0] = pos; pos++; }
  if (f1) { occ_m[pos] = base + 1; inv[base + 1] = pos; pos++; }
  if (f2) { occ_m[pos] = base + 2; inv[base + 2] = pos; pos++; }
  if (f3) { occ_m[pos] = base + 3; inv[base + 3] = pos; pos++; }
  if (t == 1023) noccPtr[0] = buf[1023];
  __syncthreads();

  // ---- phase 2: selection buckets (512) ----
  int v = (t < SBLK) ? selcnt[t] : 0;
  buf[t] = v;
  __syncthreads();
  for (int off = 1; off < 1024; off <<= 1) {
    int add = (t >= off) ? buf[t - off] : 0;
    __syncthreads();
    buf[t] += add;
    __syncthreads();
  }
  if (t < SBLK) {
    seloff[t + 1] = buf[t];
    selpos[t] = buf[t] - v;
    if (t == 0) seloff[0] = 0;
  }
  __syncthreads();

  // ---- phase 3: window buckets (729) ----
  int v2 = (t < NW3) ? wincnt[t] : 0;
  buf[t] = v2;
  __syncthreads();
  for (int off = 1; off < 1024; off <<= 1) {
    int add = (t >= off) ? buf[t - off] : 0;
    __syncthreads();
    buf[t] += add;
    __syncthreads();
  }
  if (t < NW3) {
    winoff[t + 1] = buf[t];
    winpos[t] = buf[t] - v2;
    if (t == 0) winoff[0] = 0;
  }
}

// =========================================================================
// scatter tokens into buckets
// =========================================================================
__global__ __launch_bounds__(256) void scatter(
    const int* __restrict__ sbid, const int* __restrict__ wid,
    int* __restrict__ selpos, int* __restrict__ winpos,
    int* __restrict__ sellist, int* __restrict__ winlist) {
  int n = blockIdx.x * 256 + threadIdx.x;
  if (n >= NT) return;
  int p = atomicAdd(&selpos[sbid[n]], 1);
  sellist[p] = n;
  int p2 = atomicAdd(&winpos[wid[n]], 1);
  winlist[p2] = n;
}

// =========================================================================
// generic f32 GEMM: C[rows,512] = A[rows,512] @ B[512,512]
// =========================================================================
__global__ __launch_bounds__(256) void gemm512(
    const float* __restrict__ A, const float* __restrict__ B, float* __restrict__ C,
    const int* __restrict__ nrowsPtr, int nrowsConst) {
  int nrows = nrowsPtr ? *nrowsPtr : nrowsConst;
  int rb = blockIdx.x, cb = blockIdx.y;
  int row0 = rb * 64, col0 = cb * 64;
  if (row0 >= nrows) return;
  __shared__ float As[64][17];
  __shared__ float Bs[16][68];
  int t = threadIdx.x;
  int tx = t & 15, ty = t >> 4;
  float acc[4][4] = {};
  for (int k0 = 0; k0 < 512; k0 += 16) {
    {
      int idx = t * 4; int r = idx >> 4; int kk = idx & 15;
      int gr = row0 + r;
      float4 va = (gr < nrows) ? *(const float4*)(A + (size_t)gr * 512 + k0 + kk)
                               : make_float4(0.f, 0.f, 0.f, 0.f);
      As[r][kk] = va.x; As[r][kk + 1] = va.y; As[r][kk + 2] = va.z; As[r][kk + 3] = va.w;
    }
    {
      int idx = t * 4; int kk = idx >> 6; int cc = idx & 63;
      float4 vb = *(const float4*)(B + (size_t)(k0 + kk) * 512 + col0 + cc);
      Bs[kk][cc] = vb.x; Bs[kk][cc + 1] = vb.y; Bs[kk][cc + 2] = vb.z; Bs[kk][cc + 3] = vb.w;
    }
    __syncthreads();
#pragma unroll
    for (int kk = 0; kk < 16; ++kk) {
      float a0 = As[ty * 4 + 0][kk], a1 = As[ty * 4 + 1][kk],
            a2 = As[ty * 4 + 2][kk], a3 = As[ty * 4 + 3][kk];
      float b0 = Bs[kk][tx * 4 + 0], b1 = Bs[kk][tx * 4 + 1],
            b2 = Bs[kk][tx * 4 + 2], b3 = Bs[kk][tx * 4 + 3];
      acc[0][0] += a0 * b0; acc[0][1] += a0 * b1; acc[0][2] += a0 * b2; acc[0][3] += a0 * b3;
      acc[1][0] += a1 * b0; acc[1][1] += a1 * b1; acc[1][2] += a1 * b2; acc[1][3] += a1 * b3;
      acc[2][0] += a2 * b0; acc[2][1] += a2 * b1; acc[2][2] += a2 * b2; acc[2][3] += a2 * b3;
      acc[3][0] += a3 * b0; acc[3][1] += a3 * b1; acc[3][2] += a3 * b2; acc[3][3] += a3 * b3;
    }
    __syncthreads();
  }
#pragma unroll
  for (int i = 0; i < 4; ++i) {
    int r = row0 + ty * 4 + i;
    if (r < nrows) {
#pragma unroll
      for (int j = 0; j < 4; ++j)
        C[(size_t)r * 512 + col0 + tx * 4 + j] = acc[i][j];
    }
  }
}

// =========================================================================
// gate: sigmoid(feats @ Wg)   Wg:[512,3]
// =========================================================================
__global__ __launch_bounds__(256) void gatek(
    const float* __restrict__ feats, const float* __restrict__ Wg,
    float* __restrict__ gates) {
  int idx = blockIdx.x * 256 + threadIdx.x;
  if (idx >= NT * 3) return;
  int n = idx / 3, g = idx % 3;
  const float* fp = feats + (size_t)n * 512;
  float s = 0.f;
  for (int i = 0; i < 512; ++i) s += fp[i] * Wg[i * 3 + g];
  gates[idx] = 1.f / (1.f + __expf(-s));
}

// =========================================================================
// segment accumulation into compacted block means (pre-division)
// =========================================================================
__global__ __launch_bounds__(256) void accum(
    const float* __restrict__ kf, const float* __restrict__ vf,
    const float* __restrict__ pe, const int* __restrict__ bid,
    const int* __restrict__ ibid, const int* __restrict__ inv,
    float* __restrict__ ksum, float* __restrict__ vsum) {
  int n = blockIdx.x;
  int t = threadIdx.x;
  int i = inv[bid[n]];
  const float* kp = kf + (size_t)n * 512;
  const float* vp = vf + (size_t)n * 512;
  const float* pp = pe + (size_t)ibid[n] * 512;
  float* kd = ksum + (size_t)i * 512;
  float* vd = vsum + (size_t)i * 512;
  atomicAdd(&kd[t], kp[t] + pp[t]);
  atomicAdd(&kd[t + 256], kp[t + 256] + pp[t + 256]);
  atomicAdd(&vd[t], vp[t]);
  atomicAdd(&vd[t + 256], vp[t + 256]);
}

__global__ __launch_bounds__(256) void divide_means(
    float* __restrict__ ksum, float* __restrict__ vsum,
    const int* __restrict__ occ_m, const int* __restrict__ cnt,
    const int* __restrict__ noccPtr) {
  int idx = blockIdx.x * 256 + threadIdx.x;
  int i = idx >> 9;
  if (i >= *noccPtr) return;
  float rinv = 1.f / (float)cnt[occ_m[i]];
  ksum[idx] *= rinv;
  vsum[idx] *= rinv;
}

// =========================================================================
// transpose compressed keys: ckT[d][key] (KPAD stride) from ckc[key][d]
// =========================================================================
__global__ __launch_bounds__(256) void transp(
    const float* __restrict__ src, float* __restrict__ dst,
    const int* __restrict__ noccPtr) {
  __shared__ float tile[64][65];
  int nocc = *noccPtr;
  int k0 = blockIdx.x * 64;   // key tile
  int d0 = blockIdx.y * 64;   // dim tile
  int c = threadIdx.x & 63, r0 = (threadIdx.x >> 6) * 16;
  for (int r = 0; r < 16; ++r) {
    int key = k0 + r0 + r;
    tile[r0 + r][c] = (key < nocc) ? src[(size_t)key * 512 + d0 + c] : 0.f;
  }
  __syncthreads();
  for (int r = 0; r < 16; ++r)
    dst[(size_t)(d0 + r0 + r) * KPAD + k0 + c] = tile[c][r0 + r];
}

// =========================================================================
// compressed attention v3: 1024 threads = 16 waves (8 heads x 2 key-halves).
// QK uses coalesced ckT dword loads + wave-uniform q scalar loads (no LDS).
// Shift-free softmax (scores bounded). pmat LDS round-trip for PV and
// head-pooled selection scores; in-kernel top-8. fused = gate0 * out_c.
// =========================================================================
__global__ __launch_bounds__(1024) void cattn(
    const float* __restrict__ q, const float* __restrict__ ckT,
    const float* __restrict__ cv, const int* __restrict__ occ_m,
    const int* __restrict__ noccPtr, const float* __restrict__ gates,
    float* __restrict__ fused, int* __restrict__ topk_out) {
  __shared__ float selsc[8 * 512];      // 16 KB
  __shared__ float pmat[8][8][128];     // 32 KB  (reused as opart at end)
  __shared__ float lred[16][8];
  __shared__ int   sid_l[128];
  __shared__ float redV[8];
  __shared__ int   redI[8];

  const int n0 = blockIdx.x * 8;
  const int t = threadIdx.x;
  const int nocc = *noccPtr;
  const int w = t >> 6;
  const int h    = __builtin_amdgcn_readfirstlane(w & 7);
  const int half = __builtin_amdgcn_readfirstlane(w >> 3);
  const int l = t & 63;

  for (int idx = t; idx < 4096; idx += 1024) selsc[idx] = 0.f;
  __syncthreads();

  const float* ckTh = ckT + (size_t)h * 64 * KPAD;
  const size_t qbase = (size_t)n0 * 512 + h * 64;

  // ---- pass A: l = sum(exp(sc)) per (head, tok) ----
  float lacc[8];
#pragma unroll
  for (int tok = 0; tok < 8; ++tok) lacc[tok] = 0.f;

  for (int i0 = 0; i0 < nocc; i0 += 128) {
    int i = i0 + half * 64 + l;
    if (i < nocc) {
      float sacc[8];
#pragma unroll
      for (int tok = 0; tok < 8; ++tok) sacc[tok] = 0.f;
      for (int c = 0; c < 8; ++c) {
#pragma unroll
        for (int dd = 0; dd < 8; ++dd) {
          float kv = ckTh[(size_t)(c * 8 + dd) * KPAD + i];
#pragma unroll
          for (int tok = 0; tok < 8; ++tok)
            sacc[tok] += kv * q[qbase + (size_t)tok * 512 + c * 8 + dd];
        }
      }
#pragma unroll
      for (int tok = 0; tok < 8; ++tok)
        lacc[tok] += __expf(sacc[tok] * 0.125f);
    }
  }
#pragma unroll
  for (int tok = 0; tok < 8; ++tok) {
    float l2 = lacc[tok];
#pragma unroll
    for (int s2 = 32; s2; s2 >>= 1) l2 += __shfl_xor(l2, s2, 64);
    if (l == 0) lred[w][tok] = l2;
  }
  __syncthreads();
  float rl[8];
#pragma unroll
  for (int tok = 0; tok < 8; ++tok)
    rl[tok] = 1.f / (lred[h][tok] + lred[h + 8][tok]);

  // ---- pass B: p, PV, selection scores ----
  float o[8];
#pragma unroll
  for (int tok = 0; tok < 8; ++tok) o[tok] = 0.f;

  for (int i0 = 0; i0 < nocc; i0 += 128) {
    int lim = min(128, nocc - i0);
    int i = i0 + half * 64 + l;
    float p[8];
    if (i < nocc) {
      float sacc[8];
#pragma unroll
      for (int tok = 0; tok < 8; ++tok) sacc[tok] = 0.f;
      for (int c = 0; c < 8; ++c) {
#pragma unroll
        for (int dd = 0; dd < 8; ++dd) {
          float kv = ckTh[(size_t)(c * 8 + dd) * KPAD + i];
#pragma unroll
          for (int tok = 0; tok < 8; ++tok)
            sacc[tok] += kv * q[qbase + (size_t)tok * 512 + c * 8 + dd];
        }
      }
#pragma unroll
      for (int tok = 0; tok < 8; ++tok)
        p[tok] = __expf(sacc[tok] * 0.125f) * rl[tok];
    }
    __syncthreads();   // prior tile's pmat fully consumed
    if (i < nocc) {
#pragma unroll
      for (int tok = 0; tok < 8; ++tok) pmat[h][tok][half * 64 + l] = p[tok];
    }
    if (t < 128 && t < lim) {
      int mm2 = occ_m[i0 + t];
      sid_l[t] = (((mm2 >> 8) >> 1) << 6) | ((((mm2 >> 4) & 15) >> 1) << 3) | ((mm2 & 15) >> 1);
    }
    __syncthreads();
    // selection-score accumulation: thread = (j = t&127, tok = t>>7)
    {
      int j = t & 127, tk = t >> 7;
      if (j < lim) {
        float ps = 0.f;
#pragma unroll
        for (int hh = 0; hh < 8; ++hh) ps += pmat[hh][tk][j];
        atomicAdd(&selsc[tk * 512 + sid_l[j]], ps);
      }
    }
    // PV: lane = output dim; this wave covers its key-half of the tile
    {
      int cnt_half = lim - half * 64;
      cnt_half = cnt_half < 0 ? 0 : (cnt_half > 64 ? 64 : cnt_half);
      const float* cvp = cv + (size_t)(i0 + half * 64) * 512 + h * 64 + l;
      int g4 = cnt_half >> 2;
      for (int g = 0; g < g4; ++g) {
        float v0 = cvp[(size_t)(g * 4 + 0) * 512];
        float v1 = cvp[(size_t)(g * 4 + 1) * 512];
        float v2 = cvp[(size_t)(g * 4 + 2) * 512];
        float v3 = cvp[(size_t)(g * 4 + 3) * 512];
#pragma unroll
        for (int tok = 0; tok < 8; ++tok) {
          float4 pm = *(const float4*)(&pmat[h][tok][half * 64 + g * 4]);
          o[tok] += pm.x * v0 + pm.y * v1 + pm.z * v2 + pm.w * v3;
        }
      }
      for (int j = g4 * 4; j < cnt_half; ++j) {
        float v = cvp[(size_t)j * 512];
#pragma unroll
        for (int tok = 0; tok < 8; ++tok) o[tok] += pmat[h][tok][half * 64 + j] * v;
      }
    }
  }

  // combine the two key-halves' partial o, write fused = gate0 * out_c
  __syncthreads();
  float* opart = &pmat[0][0][0];
  if (half == 1) {
#pragma unroll
    for (int tok = 0; tok < 8; ++tok) opart[(h * 8 + tok) * 64 + l] = o[tok];
  }
  __syncthreads();
  if (half == 0) {
#pragma unroll
    for (int tok = 0; tok < 8; ++tok) {
      float g0 = gates[(n0 + tok) * 3 + 0];
      fused[(size_t)(n0 + tok) * 512 + h * 64 + l] =
          g0 * (o[tok] + opart[(h * 8 + tok) * 64 + l]);
    }
  }
  __syncthreads();

  // ---- top-8 selection blocks per token (value desc, index asc ties) ----
  for (int tok = 0; tok < 8; ++tok) {
    float* sp = selsc + tok * 512;
    for (int k = 0; k < 8; ++k) {
      float bv = NEGI; int bi = 1 << 30;
      if (t < 512) { bv = sp[t]; bi = t; }
#pragma unroll
      for (int s2 = 32; s2; s2 >>= 1) {
        float ov = __shfl_xor(bv, s2, 64);
        int oi = __shfl_xor(bi, s2, 64);
        if (ov > bv || (ov == bv && oi < bi)) { bv = ov; bi = oi; }
      }
      if (l == 0 && w < 8) { redV[w] = bv; redI[w] = bi; }
      __syncthreads();
      if (t == 0) {
        float cbv = redV[0]; int cbi = redI[0];
        for (int w2 = 1; w2 < 8; ++w2)
          if (redV[w2] > cbv || (redV[w2] == cbv && redI[w2] < cbi)) { cbv = redV[w2]; cbi = redI[w2]; }
        topk_out[(n0 + tok) * 8 + k] = cbi;
        sp[cbi] = NEGI;
      }
      __syncthreads();
    }
  }
}

// =========================================================================
// selection + window attention (sparse, bucketed), adds into fused
// =========================================================================
__global__ __launch_bounds__(64) void selwin(
    const float* __restrict__ q, const float* __restrict__ kf,
    const float* __restrict__ vf, const int* __restrict__ topk,
    const int* __restrict__ seloff, const int* __restrict__ sellist,
    const int* __restrict__ winoff, const int* __restrict__ winlist,
    const int* __restrict__ wid_tok, const float* __restrict__ gates,
    float* __restrict__ fused) {
  int n = blockIdx.x, t = threadIdx.x;
  int h = t >> 3, j = t & 7;
  float q8[8];
  const float* qp = q + (size_t)n * 512 + h * 64 + j * 8;
#pragma unroll
  for (int d = 0; d < 8; ++d) q8[d] = qp[d];

  // ---- selection branch ----
  float os[8];
#pragma unroll
  for (int d = 0; d < 8; ++d) os[d] = 0.f;
  float m = NEGI, lsum = 0.f;
  for (int k = 0; k < 8; ++k) {
    int s = topk[n * 8 + k];
    int e0 = seloff[s], e1 = seloff[s + 1];
    for (int idx = e0; idx < e1; ++idx) {
      int tj = sellist[idx];
      const float* kp = kf + (size_t)tj * 512 + h * 64 + j * 8;
      float part = 0.f;
#pragma unroll
      for (int d = 0; d < 8; ++d) part += q8[d] * kp[d];
      part += __shfl_xor(part, 1, 64);
      part += __shfl_xor(part, 2, 64);
      part += __shfl_xor(part, 4, 64);
      float sc = part * 0.125f;
      float nm = fmaxf(m, sc);
      float scale = __expf(m - nm);
      float pv = __expf(sc - nm);
      const float* vp = vf + (size_t)tj * 512 + h * 64 + j * 8;
      lsum = lsum * scale + pv;
#pragma unroll
      for (int d = 0; d < 8; ++d) os[d] = os[d] * scale + pv * vp[d];
      m = nm;
    }
  }
  {
    float rl = (lsum > 0.f) ? 1.f / lsum : 0.f;
#pragma unroll
    for (int d = 0; d < 8; ++d) os[d] *= rl;
  }

  // ---- window branch ----
  float ow[8];
#pragma unroll
  for (int d = 0; d < 8; ++d) ow[d] = 0.f;
  m = NEGI; lsum = 0.f;
  int w = wid_tok[n];
  int e0 = winoff[w], e1 = winoff[w + 1];
  for (int idx = e0; idx < e1; ++idx) {
    int tj = winlist[idx];
    const float* kp = kf + (size_t)tj * 512 + h * 64 + j * 8;
    float part = 0.f;
#pragma unroll
    for (int d = 0; d < 8; ++d) part += q8[d] * kp[d];
    part += __shfl_xor(part, 1, 64);
    part += __shfl_xor(part, 2, 64);
    part += __shfl_xor(part, 4, 64);
    float sc = part * 0.125f;
    float nm = fmaxf(m, sc);
    float scale = __expf(m - nm);
    float pv = __expf(sc - nm);
    const float* vp = vf + (size_t)tj * 512 + h * 64 + j * 8;
    lsum = lsum * scale + pv;
#pragma unroll
    for (int d = 0; d < 8; ++d) ow[d] = ow[d] * scale + pv * vp[d];
    m = nm;
  }
  {
    float rl = (lsum > 0.f) ? 1.f / lsum : 0.f;
#pragma unroll
    for (int d = 0; d < 8; ++d) ow[d] *= rl;
  }

  float g1 = gates[n * 3 + 1], g2 = gates[n * 3 + 2];
  float* fp = fused + (size_t)n * 512 + h * 64 + j * 8;
#pragma unroll
  for (int d = 0; d < 8; ++d) fp[d] += g1 * os[d] + g2 * ow[d];
}

// =========================================================================
// launcher
// =========================================================================
extern "C" void kernel_launch(void* const* d_in, const int* in_sizes, int n_in,
                              void* d_out, int out_size, void* d_ws, size_t ws_size,
                              hipStream_t stream) {
  const float* feats = (const float*)d_in[0];
  const int* coords  = (const int*)d_in[1];
  const float* Wq  = (const float*)d_in[2];
  const float* Wk  = (const float*)d_in[3];
  const float* Wv  = (const float*)d_in[4];
  const float* Wo  = (const float*)d_in[5];
  const float* Wck = (const float*)d_in[6];
  const float* Wcv = (const float*)d_in[7];
  const float* pe  = (const float*)d_in[8];
  const float* Wg  = (const float*)d_in[9];
  float* out = (float*)d_out;

  char* p = (char*)d_ws;
  auto alloc = [&](size_t bytes) -> char* {
    char* r = p;
    p += (bytes + 255) & ~(size_t)255;
    return r;
  };
  float* q     = (float*)alloc((size_t)NT * 512 * 4);
  float* kf    = (float*)alloc((size_t)NT * 512 * 4);
  float* vf    = (float*)alloc((size_t)NT * 512 * 4);
  float* fused = (float*)alloc((size_t)NT * 512 * 4);
  float* zf    = (float*)alloc((size_t)2 * NT * 512 * 4);  // ckbar|cvbar (zeroed)
  float* ckbar = zf;
  float* cvbar = zf + (size_t)NT * 512;
  float* ckc   = (float*)alloc((size_t)NT * 512 * 4);
  float* cvc   = (float*)alloc((size_t)NT * 512 * 4);
  float* ckT   = (float*)alloc((size_t)512 * KPAD * 4);
  float* gates = (float*)alloc((size_t)NT * 3 * 4);
  int* zi      = (int*)alloc((size_t)(MBLK + SBLK + NW3) * 4);  // cnt|selcnt|wincnt (zeroed)
  int* cnt = zi;
  int* selcnt = zi + MBLK;
  int* wincnt = zi + MBLK + SBLK;
  int* inv     = (int*)alloc((size_t)MBLK * 4);
  int* occ     = (int*)alloc((size_t)NT * 4);
  int* nocc    = (int*)alloc(4);
  int* bid     = (int*)alloc((size_t)NT * 4);
  int* sbid    = (int*)alloc((size_t)NT * 4);
  int* wid     = (int*)alloc((size_t)NT * 4);
  int* ibid    = (int*)alloc((size_t)NT * 4);
  int* seloff  = (int*)alloc((size_t)(SBLK + 1) * 4);
  int* selpos  = (int*)alloc((size_t)SBLK * 4);
  int* sellist = (int*)alloc((size_t)NT * 4);
  int* winoff  = (int*)alloc((size_t)(NW3 + 1) * 4);
  int* winpos  = (int*)alloc((size_t)NW3 * 4);
  int* winlist = (int*)alloc((size_t)NT * 4);
  int* topk    = (int*)alloc((size_t)NT * 8 * 4);

  hipMemsetAsync(zf, 0, (size_t)2 * NT * 512 * 4, stream);
  hipMemsetAsync(zi, 0, (size_t)(MBLK + SBLK + NW3) * 4, stream);

  token_prep<<<8, 256, 0, stream>>>(coords, bid, sbid, wid, ibid, cnt, selcnt, wincnt);
  scan_all<<<1, 1024, 0, stream>>>(cnt, occ, inv, nocc, selcnt, seloff, selpos,
                                   wincnt, winoff, winpos);
  scatter<<<8, 256, 0, stream>>>(sbid, wid, selpos, winpos, sellist, winlist);

  dim3 gg(32, 8);
  gemm512<<<gg, 256, 0, stream>>>(feats, Wq, q, nullptr, NT);
  gemm512<<<gg, 256, 0, stream>>>(feats, Wk, kf, nullptr, NT);
  gemm512<<<gg, 256, 0, stream>>>(feats, Wv, vf, nullptr, NT);
  gatek<<<24, 256, 0, stream>>>(feats, Wg, gates);

  accum<<<NT, 256, 0, stream>>>(kf, vf, pe, bid, ibid, inv, ckbar, cvbar);
  divide_means<<<4096, 256, 0, stream>>>(ckbar, cvbar, occ, cnt, nocc);
  gemm512<<<gg, 256, 0, stream>>>(ckbar, Wck, ckc, nocc, 0);
  gemm512<<<gg, 256, 0, stream>>>(cvbar, Wcv, cvc, nocc, 0);
  transp<<<dim3(32, 8), 256, 0, stream>>>(ckc, ckT, nocc);

  cattn<<<256, 1024, 0, stream>>>(q, ckT, cvc, occ, nocc, gates, fused, topk);
  selwin<<<NT, 64, 0, stream>>>(q, kf, vf, topk, seloff, sellist, winoff, winlist,
                                wid, gates, fused);
  gemm512<<<gg, 256, 0, stream>>>(fused, Wo, out, nullptr, NT);
}